// Round 1
// baseline (141.833 us; speedup 1.0000x reference)
//
#include <hip/hip_runtime.h>

// Problem constants (fixed by the reference):
//   x: [B=2, D=32, 256,256,16] f32 ; N = 256*256*16 = 2^20 per row
//   mean over D, top-K=500 per row, out[b,n] = selected ? 10*mean : 0
#define B 2
#define D 32
#define NLOG 20
#define N (1 << NLOG)
#define N4 (N / 4)            // 262144 float4 per row
#define KSEL 500
#define CAP 32768             // candidate capacity per row (expect ~3K)
#define TIE_CAP 2048
#define HBINS 2048

// workspace layout (bytes)
#define OFF_MEAN 0u
#define OFF_HIST 8388608u                   // B*2048*4 = 16384
#define OFF_CKEY (OFF_HIST + 16384u)        // B*CAP*4 = 262144
#define OFF_CIDX (OFF_CKEY + 262144u)       // 262144
#define OFF_CCNT (OFF_CIDX + 262144u)       // 64 (padded)
#define OFF_META (OFF_CCNT + 64u)           // B*8*4 = 64
#define OFF_SEL  (OFF_META + 64u)           // B*512*4 = 4096
#define WS_END   (OFF_SEL + 4096u)
#define ZERO_BYTES (WS_END - OFF_HIST)

// order-preserving f32 -> u32 key (ascending)
__device__ __forceinline__ unsigned xkey(float f) {
    unsigned u = __float_as_uint(f);
    return (u & 0x80000000u) ? ~u : (u | 0x80000000u);
}

// ---------------------------------------------------------------------------
// Kernel A: mean over D (sequential accumulation order, matching numpy's
// outer-axis reduction) + histogram of top-11 key bits.
// grid = B*N4/256 blocks of 256; each thread owns one float4 (4 n's).
// ---------------------------------------------------------------------------
__global__ __launch_bounds__(256) void mean_hist_kernel(
    const float4* __restrict__ x, float4* __restrict__ mean,
    unsigned* __restrict__ hist)
{
    __shared__ unsigned lh[HBINS];
    const int tid = threadIdx.x;
    for (int i = tid; i < HBINS; i += 256) lh[i] = 0;
    __syncthreads();

    const int g  = blockIdx.x * 256 + tid;   // [0, B*N4)
    const int b  = g >> 18;                  // N4 = 2^18
    const int n4 = g & (N4 - 1);
    const float4* xb = x + ((long)b << 23);  // b * D * N4

    float4 acc = xb[n4];
    for (int d = 1; d < D; ++d) {
        float4 v = xb[((long)d << 18) + n4];
        acc.x += v.x; acc.y += v.y; acc.z += v.z; acc.w += v.w;
    }
    acc.x *= 0.03125f; acc.y *= 0.03125f; acc.z *= 0.03125f; acc.w *= 0.03125f;
    mean[g] = acc;

    atomicAdd(&lh[xkey(acc.x) >> 21], 1u);
    atomicAdd(&lh[xkey(acc.y) >> 21], 1u);
    atomicAdd(&lh[xkey(acc.z) >> 21], 1u);
    atomicAdd(&lh[xkey(acc.w) >> 21], 1u);
    __syncthreads();

    unsigned* gh = hist + b * HBINS;
    for (int i = tid; i < HBINS; i += 256)
        if (lh[i]) atomicAdd(&gh[i], lh[i]);
}

// ---------------------------------------------------------------------------
// Kernel B: find the histogram bin containing the K-th largest. grid=B x 256.
// ---------------------------------------------------------------------------
__global__ __launch_bounds__(256) void select_bin_kernel(
    const unsigned* __restrict__ hist, unsigned* __restrict__ meta)
{
    __shared__ unsigned h[HBINS];
    __shared__ unsigned ssum[256];
    const int b = blockIdx.x, t = threadIdx.x;
    const unsigned* gh = hist + b * HBINS;
    for (int i = t; i < HBINS; i += 256) h[i] = gh[i];
    __syncthreads();
    unsigned s = 0;
    for (int j = 0; j < 8; ++j) s += h[t * 8 + j];
    ssum[t] = s;
    __syncthreads();
    unsigned suf = 0;
    for (int u = t + 1; u < 256; ++u) suf += ssum[u];
    unsigned cum = suf;                       // count of elements in bins above
    for (int j = 7; j >= 0; --j) {
        const int bin = t * 8 + j;
        const unsigned c = h[bin];
        if (cum < KSEL && cum + c >= KSEL) meta[b * 8 + 0] = (unsigned)bin;
        cum += c;
    }
}

// ---------------------------------------------------------------------------
// Kernel C: collect candidates (bin >= boundary bin). grid = B*N4/256 x 256.
// ---------------------------------------------------------------------------
__global__ __launch_bounds__(256) void collect_kernel(
    const float4* __restrict__ mean, const unsigned* __restrict__ meta,
    unsigned* __restrict__ ckey, unsigned* __restrict__ cidx,
    unsigned* __restrict__ ccnt)
{
    const int g  = blockIdx.x * 256 + threadIdx.x;
    const int b  = g >> 18;
    const int n4 = g & (N4 - 1);
    const unsigned bin1 = meta[b * 8 + 0];
    const float4 m = mean[g];
    const float mv[4] = {m.x, m.y, m.z, m.w};
#pragma unroll
    for (int j = 0; j < 4; ++j) {
        const unsigned key = xkey(mv[j]);
        if ((key >> 21) >= bin1) {
            const unsigned p = atomicAdd(&ccnt[b], 1u);
            if (p < CAP) {
                ckey[b * CAP + p] = key;
                cidx[b * CAP + p] = (unsigned)(n4 * 4 + j);
            }
        }
    }
}

// ---------------------------------------------------------------------------
// Kernel D: exact K-th key via 3-pass radix select over candidates, plus
// tie resolution by ascending index (jax top_k tie-break). grid=B x 1024.
// ---------------------------------------------------------------------------
__global__ __launch_bounds__(1024) void radix_select_kernel(
    const unsigned* __restrict__ ckey, const unsigned* __restrict__ cidx,
    const unsigned* __restrict__ ccnt, unsigned* __restrict__ meta,
    unsigned* __restrict__ sel)
{
    __shared__ unsigned hist[HBINS];
    __shared__ unsigned ssum[256];
    __shared__ unsigned sfound[2];
    __shared__ unsigned tcnt;
    __shared__ unsigned tlist[TIE_CAP];

    const int b = blockIdx.x, t = threadIdx.x;
    unsigned M = ccnt[b]; if (M > CAP) M = CAP;
    const unsigned* keys = ckey + b * CAP;
    const unsigned* idxs = cidx + b * CAP;

    unsigned r = KSEL;       // rank sought within current prefix group
    unsigned prefix = 0;

    for (int pass = 0; pass < 3; ++pass) {
        const int nb = (pass == 2) ? 1024 : 2048;
        for (int i = t; i < nb; i += 1024) hist[i] = 0;
        __syncthreads();
        for (unsigned i = t; i < M; i += 1024) {
            const unsigned key = keys[i];
            const bool match = (pass == 0) ? true
                             : (pass == 1) ? ((key >> 21) == (prefix >> 21))
                                           : ((key >> 10) == (prefix >> 10));
            if (match) {
                const unsigned dg = (pass == 0) ? (key >> 21)
                                  : (pass == 1) ? ((key >> 10) & 0x7FFu)
                                                : (key & 0x3FFu);
                atomicAdd(&hist[dg], 1u);
            }
        }
        __syncthreads();
        const int chunk = nb / 256;
        if (t < 256) {
            unsigned s = 0;
            for (int j = 0; j < chunk; ++j) s += hist[t * chunk + j];
            ssum[t] = s;
        }
        __syncthreads();
        if (t < 256) {
            unsigned suf = 0;
            for (int u = t + 1; u < 256; ++u) suf += ssum[u];
            unsigned cum = suf;
            for (int j = chunk - 1; j >= 0; --j) {
                const int g2 = t * chunk + j;
                const unsigned c = hist[g2];
                if (cum < r && cum + c >= r) { sfound[0] = (unsigned)g2; sfound[1] = cum; }
                cum += c;
            }
        }
        __syncthreads();
        const unsigned fd = sfound[0], ca = sfound[1];
        r -= ca;
        prefix |= fd << ((pass == 0) ? 21 : (pass == 1) ? 10 : 0);
        __syncthreads();
    }
    // prefix = T (key of the K-th largest); r = # of ties to take (by asc idx)

    if (t == 0) tcnt = 0;
    __syncthreads();
    for (unsigned i = t; i < M; i += 1024) {
        if (keys[i] == prefix) {
            const unsigned p = atomicAdd(&tcnt, 1u);
            if (p < TIE_CAP) tlist[p] = i;
        }
    }
    __syncthreads();
    unsigned E = tcnt; if (E > TIE_CAP) E = TIE_CAP;
    for (unsigned j = t; j < E; j += 1024) {
        const unsigned idxj = idxs[tlist[j]];
        unsigned rank = 0;
        for (unsigned k2 = 0; k2 < E; ++k2) rank += (idxs[tlist[k2]] < idxj) ? 1u : 0u;
        if (rank < r) sel[b * 512 + rank] = idxj;
    }
    if (t == 0) {
        meta[b * 8 + 1] = prefix;                 // T key
        meta[b * 8 + 2] = r;                      // needed ties
        meta[b * 8 + 3] = (prefix & 0x80000000u) ? (prefix & 0x7FFFFFFFu)
                                                 : ~prefix;  // float bits of T
    }
}

// ---------------------------------------------------------------------------
// Kernel E: write output: key > T ? 10*mean : 0. grid = B*N4/256 x 256.
// ---------------------------------------------------------------------------
__global__ __launch_bounds__(256) void write_out_kernel(
    const float4* __restrict__ mean, const unsigned* __restrict__ meta,
    float4* __restrict__ out)
{
    const int g = blockIdx.x * 256 + threadIdx.x;
    const int b = g >> 18;
    const unsigned T = meta[b * 8 + 1];
    const float4 m = mean[g];
    float4 o;
    o.x = (xkey(m.x) > T) ? 10.0f * m.x : 0.0f;
    o.y = (xkey(m.y) > T) ? 10.0f * m.y : 0.0f;
    o.z = (xkey(m.z) > T) ? 10.0f * m.z : 0.0f;
    o.w = (xkey(m.w) > T) ? 10.0f * m.w : 0.0f;
    out[g] = o;
}

// ---------------------------------------------------------------------------
// Kernel F: write the selected ties. grid = B x 256.
// ---------------------------------------------------------------------------
__global__ __launch_bounds__(256) void tie_write_kernel(
    const unsigned* __restrict__ meta, const unsigned* __restrict__ sel,
    float* __restrict__ out)
{
    const int b = blockIdx.x;
    const unsigned needed = meta[b * 8 + 2];
    const float tv = __uint_as_float(meta[b * 8 + 3]);
    for (unsigned i = threadIdx.x; i < needed; i += 256)
        out[(long)b * N + sel[b * 512 + i]] = 10.0f * tv;
}

extern "C" void kernel_launch(void* const* d_in, const int* in_sizes, int n_in,
                              void* d_out, int out_size, void* d_ws, size_t ws_size,
                              hipStream_t stream)
{
    const float4* x = (const float4*)d_in[0];
    char* wsb = (char*)d_ws;
    float4*   mean = (float4*)(wsb + OFF_MEAN);
    unsigned* hist = (unsigned*)(wsb + OFF_HIST);
    unsigned* ckey = (unsigned*)(wsb + OFF_CKEY);
    unsigned* cidx = (unsigned*)(wsb + OFF_CIDX);
    unsigned* ccnt = (unsigned*)(wsb + OFF_CCNT);
    unsigned* meta = (unsigned*)(wsb + OFF_META);
    unsigned* sel  = (unsigned*)(wsb + OFF_SEL);

    hipMemsetAsync(wsb + OFF_HIST, 0, ZERO_BYTES, stream);

    const int grid = B * N4 / 256;   // 2048
    mean_hist_kernel<<<grid, 256, 0, stream>>>(x, mean, hist);
    select_bin_kernel<<<B, 256, 0, stream>>>(hist, meta);
    collect_kernel<<<grid, 256, 0, stream>>>(mean, meta, ckey, cidx, ccnt);
    radix_select_kernel<<<B, 1024, 0, stream>>>(ckey, cidx, ccnt, meta, sel);
    write_out_kernel<<<grid, 256, 0, stream>>>(mean, meta, (float4*)d_out);
    tie_write_kernel<<<B, 256, 0, stream>>>(meta, sel, (float*)d_out);
}

// Round 2
// 140.402 us; speedup vs baseline: 1.0102x; 1.0102x over previous
//
#include <hip/hip_runtime.h>

// Problem constants (fixed by the reference):
//   x: [B=2, D=32, 256,256,16] f32 ; N = 256*256*16 = 2^20 per row
//   mean over D, top-K=500 per row, out[b,n] = selected ? 10*mean : 0
#define B 2
#define D 32
#define NLOG 20
#define N (1 << NLOG)
#define N4 (N / 4)            // 262144 float4 per row
#define KSEL 500
#define CAP 32768             // candidate capacity per row (expect ~1-4K)
#define TIE_CAP 2048
#define HBINS 2048

// workspace layout (bytes)
#define OFF_MEAN 0u
#define OFF_HIST 8388608u                   // B*2048*4 = 16384
#define OFF_CKEY (OFF_HIST + 16384u)        // B*CAP*4 = 262144
#define OFF_CIDX (OFF_CKEY + 262144u)       // 262144
#define OFF_CCNT (OFF_CIDX + 262144u)       // 64 (padded)
#define OFF_META (OFF_CCNT + 64u)           // B*8*4 = 64

// order-preserving f32 -> u32 key (ascending); exact bijection
__device__ __forceinline__ unsigned xkey(float f) {
    unsigned u = __float_as_uint(f);
    return (u & 0x80000000u) ? ~u : (u | 0x80000000u);
}
__device__ __forceinline__ float xkey_inv(unsigned key) {
    unsigned u = (key & 0x80000000u) ? (key & 0x7FFFFFFFu) : ~key;
    return __uint_as_float(u);
}

// ---------------------------------------------------------------------------
// Kernel Z: zero hist + ccnt (replaces slow fillBufferAligned path).
// ---------------------------------------------------------------------------
__global__ __launch_bounds__(256) void zero_kernel(
    unsigned* __restrict__ hist, unsigned* __restrict__ ccnt)
{
    const int i = blockIdx.x * 256 + threadIdx.x;
    if (i < B * HBINS) hist[i] = 0;
    if (i < 16) ccnt[i] = 0;
}

// ---------------------------------------------------------------------------
// Kernel A: mean over D (sequential accumulation, matching numpy's outer-axis
// reduction order) + histogram of top-11 key bits + zero-fill the output.
// grid = B*N4/256 blocks of 256; each thread owns one float4 (4 n's).
// ---------------------------------------------------------------------------
__global__ __launch_bounds__(256) void mean_hist_kernel(
    const float4* __restrict__ x, float4* __restrict__ mean,
    unsigned* __restrict__ hist, float4* __restrict__ out)
{
    __shared__ unsigned lh[HBINS];
    const int tid = threadIdx.x;
    for (int i = tid; i < HBINS; i += 256) lh[i] = 0;
    __syncthreads();

    const int g  = blockIdx.x * 256 + tid;   // [0, B*N4)
    const int b  = g >> 18;                  // N4 = 2^18
    const int n4 = g & (N4 - 1);
    const float4* xb = x + ((long)b << 23);  // b * D * N4

    float4 acc = xb[n4];
    for (int d = 1; d < D; ++d) {
        float4 v = xb[((long)d << 18) + n4];
        acc.x += v.x; acc.y += v.y; acc.z += v.z; acc.w += v.w;
    }
    acc.x *= 0.03125f; acc.y *= 0.03125f; acc.z *= 0.03125f; acc.w *= 0.03125f;
    mean[g] = acc;
    out[g] = make_float4(0.f, 0.f, 0.f, 0.f);   // selected few fixed up later

    atomicAdd(&lh[xkey(acc.x) >> 21], 1u);
    atomicAdd(&lh[xkey(acc.y) >> 21], 1u);
    atomicAdd(&lh[xkey(acc.z) >> 21], 1u);
    atomicAdd(&lh[xkey(acc.w) >> 21], 1u);
    __syncthreads();

    unsigned* gh = hist + b * HBINS;
    for (int i = tid; i < HBINS; i += 256)
        if (lh[i]) atomicAdd(&gh[i], lh[i]);
}

// ---------------------------------------------------------------------------
// Kernel B: find the histogram bin containing the K-th largest. grid=B x 256.
// ---------------------------------------------------------------------------
__global__ __launch_bounds__(256) void select_bin_kernel(
    const unsigned* __restrict__ hist, unsigned* __restrict__ meta)
{
    __shared__ unsigned h[HBINS];
    __shared__ unsigned ssum[256];
    const int b = blockIdx.x, t = threadIdx.x;
    const unsigned* gh = hist + b * HBINS;
    for (int i = t; i < HBINS; i += 256) h[i] = gh[i];
    __syncthreads();
    unsigned s = 0;
    for (int j = 0; j < 8; ++j) s += h[t * 8 + j];
    ssum[t] = s;
    __syncthreads();
    unsigned suf = 0;
    for (int u = t + 1; u < 256; ++u) suf += ssum[u];
    unsigned cum = suf;                       // count of elements in bins above
    for (int j = 7; j >= 0; --j) {
        const int bin = t * 8 + j;
        const unsigned c = h[bin];
        if (cum < KSEL && cum + c >= KSEL) meta[b * 8 + 0] = (unsigned)bin;
        cum += c;
    }
}

// ---------------------------------------------------------------------------
// Kernel C: collect candidates (bin >= boundary bin). grid = B*N4/256 x 256.
// mean[] is L2/L3-resident (8 MB) — cheap re-read.
// ---------------------------------------------------------------------------
__global__ __launch_bounds__(256) void collect_kernel(
    const float4* __restrict__ mean, const unsigned* __restrict__ meta,
    unsigned* __restrict__ ckey, unsigned* __restrict__ cidx,
    unsigned* __restrict__ ccnt)
{
    const int g  = blockIdx.x * 256 + threadIdx.x;
    const int b  = g >> 18;
    const int n4 = g & (N4 - 1);
    const unsigned bin1 = meta[b * 8 + 0];
    const float4 m = mean[g];
    const float mv[4] = {m.x, m.y, m.z, m.w};
#pragma unroll
    for (int j = 0; j < 4; ++j) {
        const unsigned key = xkey(mv[j]);
        if ((key >> 21) >= bin1) {
            const unsigned p = atomicAdd(&ccnt[b], 1u);
            if (p < CAP) {
                ckey[b * CAP + p] = key;
                cidx[b * CAP + p] = (unsigned)(n4 * 4 + j);
            }
        }
    }
}

// ---------------------------------------------------------------------------
// Kernel D: exact K-th key via 3-pass radix select over candidates, then
// scatter the selected outputs directly (values recovered bit-exactly from
// keys) with jax tie-break (ascending index). grid = B x 1024.
// ---------------------------------------------------------------------------
__global__ __launch_bounds__(1024) void radix_select_scatter_kernel(
    const unsigned* __restrict__ ckey, const unsigned* __restrict__ cidx,
    const unsigned* __restrict__ ccnt, float* __restrict__ out)
{
    __shared__ unsigned hist[HBINS];
    __shared__ unsigned ssum[256];
    __shared__ unsigned sfound[2];
    __shared__ unsigned tcnt;
    __shared__ unsigned tlist[TIE_CAP];

    const int b = blockIdx.x, t = threadIdx.x;
    unsigned M = ccnt[b]; if (M > CAP) M = CAP;
    const unsigned* keys = ckey + b * CAP;
    const unsigned* idxs = cidx + b * CAP;
    float* outb = out + (long)b * N;

    unsigned r = KSEL;       // rank sought within current prefix group
    unsigned prefix = 0;

    for (int pass = 0; pass < 3; ++pass) {
        const int nb = (pass == 2) ? 1024 : 2048;
        for (int i = t; i < nb; i += 1024) hist[i] = 0;
        __syncthreads();
        for (unsigned i = t; i < M; i += 1024) {
            const unsigned key = keys[i];
            const bool match = (pass == 0) ? true
                             : (pass == 1) ? ((key >> 21) == (prefix >> 21))
                                           : ((key >> 10) == (prefix >> 10));
            if (match) {
                const unsigned dg = (pass == 0) ? (key >> 21)
                                  : (pass == 1) ? ((key >> 10) & 0x7FFu)
                                                : (key & 0x3FFu);
                atomicAdd(&hist[dg], 1u);
            }
        }
        __syncthreads();
        const int chunk = nb / 256;
        if (t < 256) {
            unsigned s = 0;
            for (int j = 0; j < chunk; ++j) s += hist[t * chunk + j];
            ssum[t] = s;
        }
        __syncthreads();
        if (t < 256) {
            unsigned suf = 0;
            for (int u = t + 1; u < 256; ++u) suf += ssum[u];
            unsigned cum = suf;
            for (int j = chunk - 1; j >= 0; --j) {
                const int g2 = t * chunk + j;
                const unsigned c = hist[g2];
                if (cum < r && cum + c >= r) { sfound[0] = (unsigned)g2; sfound[1] = cum; }
                cum += c;
            }
        }
        __syncthreads();
        const unsigned fd = sfound[0], ca = sfound[1];
        r -= ca;
        prefix |= fd << ((pass == 0) ? 21 : (pass == 1) ? 10 : 0);
        __syncthreads();
    }
    // prefix = T (key of the K-th largest); r = # of ties to take (asc index)
    const unsigned T = prefix;
    const float tv = xkey_inv(T);

    if (t == 0) tcnt = 0;
    __syncthreads();
    for (unsigned i = t; i < M; i += 1024) {
        const unsigned key = keys[i];
        if (key > T) {
            outb[idxs[i]] = 10.0f * xkey_inv(key);   // strictly above: selected
        } else if (key == T) {
            const unsigned p = atomicAdd(&tcnt, 1u);
            if (p < TIE_CAP) tlist[p] = i;
        }
    }
    __syncthreads();
    unsigned E = tcnt; if (E > TIE_CAP) E = TIE_CAP;
    for (unsigned j = t; j < E; j += 1024) {
        const unsigned idxj = idxs[tlist[j]];
        unsigned rank = 0;
        for (unsigned k2 = 0; k2 < E; ++k2) rank += (idxs[tlist[k2]] < idxj) ? 1u : 0u;
        if (rank < r) outb[idxj] = 10.0f * tv;
    }
}

extern "C" void kernel_launch(void* const* d_in, const int* in_sizes, int n_in,
                              void* d_out, int out_size, void* d_ws, size_t ws_size,
                              hipStream_t stream)
{
    const float4* x = (const float4*)d_in[0];
    char* wsb = (char*)d_ws;
    float4*   mean = (float4*)(wsb + OFF_MEAN);
    unsigned* hist = (unsigned*)(wsb + OFF_HIST);
    unsigned* ckey = (unsigned*)(wsb + OFF_CKEY);
    unsigned* cidx = (unsigned*)(wsb + OFF_CIDX);
    unsigned* ccnt = (unsigned*)(wsb + OFF_CCNT);
    unsigned* meta = (unsigned*)(wsb + OFF_META);

    const int grid = B * N4 / 256;   // 2048
    zero_kernel<<<(B * HBINS + 255) / 256, 256, 0, stream>>>(hist, ccnt);
    mean_hist_kernel<<<grid, 256, 0, stream>>>(x, mean, hist, (float4*)d_out);
    select_bin_kernel<<<B, 256, 0, stream>>>(hist, meta);
    collect_kernel<<<grid, 256, 0, stream>>>(mean, meta, ckey, cidx, ccnt);
    radix_select_scatter_kernel<<<B, 1024, 0, stream>>>(ckey, cidx, ccnt, (float*)d_out);
}

// Round 3
// 103.068 us; speedup vs baseline: 1.3761x; 1.3622x over previous
//
#include <hip/hip_runtime.h>

// Problem constants (fixed by the reference):
//   x: [B=2, D=32, 256,256,16] f32 ; N = 256*256*16 = 2^20 per row
//   mean over D, top-K=500 per row, out[b,n] = selected ? 10*mean : 0
#define B 2
#define D 32
#define NLOG 20
#define N (1 << NLOG)
#define N4 (N / 4)            // 262144 float4 per row
#define KSEL 500
#define CAP 32768             // candidate capacity per row (expect ~3K)
#define TIE_CAP 2048
#define HBINS 2048
#define NREP 16               // histogram replicas (atomic-contention fix)

// workspace layout (bytes)
#define OFF_MEAN 0u
#define OFF_HIST 8388608u                     // B*NREP*2048*4 = 262144
#define OFF_CKEY (OFF_HIST + 262144u)         // B*CAP*4 = 262144
#define OFF_CIDX (OFF_CKEY + 262144u)         // 262144
#define OFF_CCNT (OFF_CIDX + 262144u)         // 64 (padded)
#define OFF_META (OFF_CCNT + 64u)             // B*8*4 = 64

// order-preserving f32 -> u32 key (ascending); exact bijection
__device__ __forceinline__ unsigned xkey(float f) {
    unsigned u = __float_as_uint(f);
    return (u & 0x80000000u) ? ~u : (u | 0x80000000u);
}
__device__ __forceinline__ float xkey_inv(unsigned key) {
    unsigned u = (key & 0x80000000u) ? (key & 0x7FFFFFFFu) : ~key;
    return __uint_as_float(u);
}

// ---------------------------------------------------------------------------
// Kernel Z: zero hist replicas + ccnt. grid = 256 x 256.
// ---------------------------------------------------------------------------
__global__ __launch_bounds__(256) void zero_kernel(
    unsigned* __restrict__ hist, unsigned* __restrict__ ccnt)
{
    const int i = blockIdx.x * 256 + threadIdx.x;
    if (i < B * NREP * HBINS) hist[i] = 0;
    if (i < 16) ccnt[i] = 0;
}

// ---------------------------------------------------------------------------
// Kernel A: mean over D (sequential accumulation, matching numpy's outer-axis
// reduction order) + replicated histogram of top-11 key bits + zero the out.
// grid = B*N4/256 blocks of 256; each thread owns one float4 (4 n's).
// ---------------------------------------------------------------------------
__global__ __launch_bounds__(256) void mean_hist_kernel(
    const float4* __restrict__ x, float4* __restrict__ mean,
    unsigned* __restrict__ hist, float4* __restrict__ out)
{
    __shared__ unsigned lh[HBINS];
    const int tid = threadIdx.x;
    for (int i = tid; i < HBINS; i += 256) lh[i] = 0;
    __syncthreads();

    const int g  = blockIdx.x * 256 + tid;   // [0, B*N4)
    const int b  = g >> 18;                  // N4 = 2^18
    const int n4 = g & (N4 - 1);
    const float4* xb = x + ((long)b << 23);  // b * D * N4

    float4 acc = xb[n4];
    for (int d = 1; d < D; ++d) {
        float4 v = xb[((long)d << 18) + n4];
        acc.x += v.x; acc.y += v.y; acc.z += v.z; acc.w += v.w;
    }
    acc.x *= 0.03125f; acc.y *= 0.03125f; acc.z *= 0.03125f; acc.w *= 0.03125f;
    mean[g] = acc;
    out[g] = make_float4(0.f, 0.f, 0.f, 0.f);   // selected few fixed up later

    atomicAdd(&lh[xkey(acc.x) >> 21], 1u);
    atomicAdd(&lh[xkey(acc.y) >> 21], 1u);
    atomicAdd(&lh[xkey(acc.z) >> 21], 1u);
    atomicAdd(&lh[xkey(acc.w) >> 21], 1u);
    __syncthreads();

    // flush to one of NREP replicas -> same-address chains /16
    unsigned* gh = hist + ((b * NREP) + (blockIdx.x & (NREP - 1))) * HBINS;
    for (int i = tid; i < HBINS; i += 256)
        if (lh[i]) atomicAdd(&gh[i], lh[i]);
}

// ---------------------------------------------------------------------------
// Kernel B: sum replicas, find bin containing the K-th largest. grid=B x 256.
// ---------------------------------------------------------------------------
__global__ __launch_bounds__(256) void select_bin_kernel(
    const unsigned* __restrict__ hist, unsigned* __restrict__ meta)
{
    __shared__ unsigned h[HBINS];
    __shared__ unsigned ssum[256];
    const int b = blockIdx.x, t = threadIdx.x;
    const unsigned* gh = hist + b * NREP * HBINS;
    for (int i = t; i < HBINS; i += 256) {
        unsigned s = 0;
        for (int r = 0; r < NREP; ++r) s += gh[r * HBINS + i];
        h[i] = s;
    }
    __syncthreads();
    unsigned s = 0;
    for (int j = 0; j < 8; ++j) s += h[t * 8 + j];
    ssum[t] = s;
    __syncthreads();
    unsigned suf = 0;
    for (int u = t + 1; u < 256; ++u) suf += ssum[u];
    unsigned cum = suf;                       // count of elements in bins above
    for (int j = 7; j >= 0; --j) {
        const int bin = t * 8 + j;
        const unsigned c = h[bin];
        if (cum < KSEL && cum + c >= KSEL) meta[b * 8 + 0] = (unsigned)bin;
        cum += c;
    }
}

// ---------------------------------------------------------------------------
// Kernel C: collect candidates (bin >= boundary bin), block-aggregated
// reservation (one global atomic per block). grid = B*N4/256 x 256.
// ---------------------------------------------------------------------------
__global__ __launch_bounds__(256) void collect_kernel(
    const float4* __restrict__ mean, const unsigned* __restrict__ meta,
    unsigned* __restrict__ ckey, unsigned* __restrict__ cidx,
    unsigned* __restrict__ ccnt)
{
    __shared__ unsigned lcnt;
    __shared__ unsigned lbase;
    __shared__ unsigned lkey[1024];
    __shared__ unsigned lidx[1024];
    const int t = threadIdx.x;
    if (t == 0) lcnt = 0;
    __syncthreads();

    const int g  = blockIdx.x * 256 + t;
    const int b  = g >> 18;
    const int n4 = g & (N4 - 1);
    const unsigned bin1 = meta[b * 8 + 0];
    const float4 m = mean[g];
    const float mv[4] = {m.x, m.y, m.z, m.w};
#pragma unroll
    for (int j = 0; j < 4; ++j) {
        const unsigned key = xkey(mv[j]);
        if ((key >> 21) >= bin1) {
            const unsigned p = atomicAdd(&lcnt, 1u);   // LDS atomic, rare
            lkey[p] = key;
            lidx[p] = (unsigned)(n4 * 4 + j);
        }
    }
    __syncthreads();
    if (t == 0) lbase = (lcnt > 0) ? atomicAdd(&ccnt[b], lcnt) : 0u;
    __syncthreads();
    const unsigned cnt = lcnt, base = lbase;
    for (unsigned j = t; j < cnt; j += 256) {
        const unsigned p = base + j;
        if (p < CAP) {
            ckey[b * CAP + p] = lkey[j];
            cidx[b * CAP + p] = lidx[j];
        }
    }
}

// ---------------------------------------------------------------------------
// Kernel D: exact K-th key via 3-pass radix select over candidates, then
// scatter the selected outputs directly (values recovered bit-exactly from
// keys) with jax tie-break (ascending index). grid = B x 1024.
// ---------------------------------------------------------------------------
__global__ __launch_bounds__(1024) void radix_select_scatter_kernel(
    const unsigned* __restrict__ ckey, const unsigned* __restrict__ cidx,
    const unsigned* __restrict__ ccnt, float* __restrict__ out)
{
    __shared__ unsigned hist[HBINS];
    __shared__ unsigned ssum[256];
    __shared__ unsigned sfound[2];
    __shared__ unsigned tcnt;
    __shared__ unsigned tlist[TIE_CAP];

    const int b = blockIdx.x, t = threadIdx.x;
    unsigned M = ccnt[b]; if (M > CAP) M = CAP;
    const unsigned* keys = ckey + b * CAP;
    const unsigned* idxs = cidx + b * CAP;
    float* outb = out + (long)b * N;

    unsigned r = KSEL;       // rank sought within current prefix group
    unsigned prefix = 0;

    for (int pass = 0; pass < 3; ++pass) {
        const int nb = (pass == 2) ? 1024 : 2048;
        for (int i = t; i < nb; i += 1024) hist[i] = 0;
        __syncthreads();
        for (unsigned i = t; i < M; i += 1024) {
            const unsigned key = keys[i];
            const bool match = (pass == 0) ? true
                             : (pass == 1) ? ((key >> 21) == (prefix >> 21))
                                           : ((key >> 10) == (prefix >> 10));
            if (match) {
                const unsigned dg = (pass == 0) ? (key >> 21)
                                  : (pass == 1) ? ((key >> 10) & 0x7FFu)
                                                : (key & 0x3FFu);
                atomicAdd(&hist[dg], 1u);
            }
        }
        __syncthreads();
        const int chunk = nb / 256;
        if (t < 256) {
            unsigned s = 0;
            for (int j = 0; j < chunk; ++j) s += hist[t * chunk + j];
            ssum[t] = s;
        }
        __syncthreads();
        if (t < 256) {
            unsigned suf = 0;
            for (int u = t + 1; u < 256; ++u) suf += ssum[u];
            unsigned cum = suf;
            for (int j = chunk - 1; j >= 0; --j) {
                const int g2 = t * chunk + j;
                const unsigned c = hist[g2];
                if (cum < r && cum + c >= r) { sfound[0] = (unsigned)g2; sfound[1] = cum; }
                cum += c;
            }
        }
        __syncthreads();
        const unsigned fd = sfound[0], ca = sfound[1];
        r -= ca;
        prefix |= fd << ((pass == 0) ? 21 : (pass == 1) ? 10 : 0);
        __syncthreads();
    }
    // prefix = T (key of the K-th largest); r = # of ties to take (asc index)
    const unsigned T = prefix;
    const float tv = xkey_inv(T);

    if (t == 0) tcnt = 0;
    __syncthreads();
    for (unsigned i = t; i < M; i += 1024) {
        const unsigned key = keys[i];
        if (key > T) {
            outb[idxs[i]] = 10.0f * xkey_inv(key);   // strictly above: selected
        } else if (key == T) {
            const unsigned p = atomicAdd(&tcnt, 1u);
            if (p < TIE_CAP) tlist[p] = i;
        }
    }
    __syncthreads();
    unsigned E = tcnt; if (E > TIE_CAP) E = TIE_CAP;
    for (unsigned j = t; j < E; j += 1024) {
        const unsigned idxj = idxs[tlist[j]];
        unsigned rank = 0;
        for (unsigned k2 = 0; k2 < E; ++k2) rank += (idxs[tlist[k2]] < idxj) ? 1u : 0u;
        if (rank < r) outb[idxj] = 10.0f * tv;
    }
}

extern "C" void kernel_launch(void* const* d_in, const int* in_sizes, int n_in,
                              void* d_out, int out_size, void* d_ws, size_t ws_size,
                              hipStream_t stream)
{
    const float4* x = (const float4*)d_in[0];
    char* wsb = (char*)d_ws;
    float4*   mean = (float4*)(wsb + OFF_MEAN);
    unsigned* hist = (unsigned*)(wsb + OFF_HIST);
    unsigned* ckey = (unsigned*)(wsb + OFF_CKEY);
    unsigned* cidx = (unsigned*)(wsb + OFF_CIDX);
    unsigned* ccnt = (unsigned*)(wsb + OFF_CCNT);
    unsigned* meta = (unsigned*)(wsb + OFF_META);

    const int grid = B * N4 / 256;   // 2048
    zero_kernel<<<256, 256, 0, stream>>>(hist, ccnt);
    mean_hist_kernel<<<grid, 256, 0, stream>>>(x, mean, hist, (float4*)d_out);
    select_bin_kernel<<<B, 256, 0, stream>>>(hist, meta);
    collect_kernel<<<grid, 256, 0, stream>>>(mean, meta, ckey, cidx, ccnt);
    radix_select_scatter_kernel<<<B, 1024, 0, stream>>>(ckey, cidx, ccnt, (float*)d_out);
}